// Round 1
// baseline (2970.418 us; speedup 1.0000x reference)
//
#include <hip/hip_runtime.h>

#define D 256
#define NCLS 40

// ---------------- CSR build ----------------

__global__ __launch_bounds__(256) void count_dst(const int* __restrict__ dst, int ne,
                                                 int* __restrict__ counts) {
    int e = blockIdx.x * 256 + threadIdx.x;
    if (e < ne) atomicAdd(&counts[dst[e]], 1);
}

// per-block inclusive scan of counts -> incl, plus block sums
__global__ __launch_bounds__(256) void scan1(const int* __restrict__ counts, int n,
                                             int* __restrict__ incl, int* __restrict__ blk_sums) {
    __shared__ int s[256];
    int tx = threadIdx.x;
    int i = blockIdx.x * 256 + tx;
    int v = (i < n) ? counts[i] : 0;
    s[tx] = v;
    __syncthreads();
    for (int off = 1; off < 256; off <<= 1) {
        int t = (tx >= off) ? s[tx - off] : 0;
        __syncthreads();
        s[tx] += t;
        __syncthreads();
    }
    if (i < n) incl[i] = s[tx];
    if (tx == 255) blk_sums[blockIdx.x] = s[255];
}

// single-block exclusive scan of block sums (nb <= 512)
__global__ __launch_bounds__(512) void scan2(const int* __restrict__ blk_sums, int nb,
                                             int* __restrict__ blk_off) {
    __shared__ int s[512];
    int tx = threadIdx.x;
    int v = (tx < nb) ? blk_sums[tx] : 0;
    s[tx] = v;
    __syncthreads();
    for (int off = 1; off < 512; off <<= 1) {
        int t = (tx >= off) ? s[tx - off] : 0;
        __syncthreads();
        s[tx] += t;
        __syncthreads();
    }
    if (tx < nb) blk_off[tx] = s[tx] - v;   // exclusive
}

// row_start[i] (holds block-local inclusive) -> global exclusive scan
__global__ __launch_bounds__(256) void scan3(int* __restrict__ row_start,
                                             const int* __restrict__ counts,
                                             const int* __restrict__ blk_off, int n) {
    int i = blockIdx.x * 256 + threadIdx.x;
    if (i < n) row_start[i] = blk_off[blockIdx.x] + row_start[i] - counts[i];
}

__global__ __launch_bounds__(256) void scatter_edges(const int* __restrict__ src,
                                                     const int* __restrict__ dst,
                                                     const float* __restrict__ w, int ne,
                                                     const int* __restrict__ row_start,
                                                     int* __restrict__ cursor,
                                                     int* __restrict__ csr_src,
                                                     float* __restrict__ csr_w) {
    int e = blockIdx.x * 256 + threadIdx.x;
    if (e >= ne) return;
    int d = dst[e];
    int pos = row_start[d] + atomicAdd(&cursor[d], 1);
    csr_src[pos] = src[e];
    csr_w[pos]   = w[e];
}

// ---------------- dense GEMM  C[M x 256] = A[M x 256] @ B[256 x 256] ----------------
// 64x64 tile, 256 threads, 4x4 per thread, K-step 16.

__global__ __launch_bounds__(256) void gemm256(const float* __restrict__ A,
                                               const float* __restrict__ B,
                                               float* __restrict__ C, int M) {
    __shared__ __align__(16) float As[16][68];  // [kk][r], stride 68 -> conflict-free writes, 272B rows (16B-mult)
    __shared__ __align__(16) float Bs[16][64];  // [kk][c]
    const int tid = threadIdx.x;
    const int tx = tid & 15, ty = tid >> 4;
    const int row0 = blockIdx.x * 64;
    const int col0 = blockIdx.y * 64;

    float acc[4][4] = {};

    for (int k0 = 0; k0 < D; k0 += 16) {
        // A tile: 64 rows x 16 k
        {
            int kk = tid & 15, r = tid >> 4;
#pragma unroll
            for (int s = 0; s < 4; s++) {
                int rr = r + s * 16;
                int grow = row0 + rr;
                As[kk][rr] = (grow < M) ? A[(size_t)grow * D + k0 + kk] : 0.f;
            }
        }
        // B tile: 16 k x 64 cols
        {
            int c = tid & 63, kk = tid >> 6;
#pragma unroll
            for (int s = 0; s < 4; s++) {
                Bs[kk + s * 4][c] = B[(size_t)(k0 + kk + s * 4) * D + col0 + c];
            }
        }
        __syncthreads();
#pragma unroll
        for (int kk = 0; kk < 16; kk++) {
            float4 a4 = *(const float4*)&As[kk][ty * 4];
            float4 b4 = *(const float4*)&Bs[kk][tx * 4];
            float a[4] = {a4.x, a4.y, a4.z, a4.w};
            float b[4] = {b4.x, b4.y, b4.z, b4.w};
#pragma unroll
            for (int i = 0; i < 4; i++)
#pragma unroll
                for (int j = 0; j < 4; j++) acc[i][j] = fmaf(a[i], b[j], acc[i][j]);
        }
        __syncthreads();
    }

#pragma unroll
    for (int i = 0; i < 4; i++) {
        int grow = row0 + ty * 4 + i;
        if (grow < M) {
            float4 v = make_float4(acc[i][0], acc[i][1], acc[i][2], acc[i][3]);
            *(float4*)&C[(size_t)grow * D + col0 + tx * 4] = v;
        }
    }
}

// ---------------- SpMM + bias + ReLU ----------------
// one block (256 threads) per dst node; thread = feature dim

__global__ __launch_bounds__(256) void spmm_bias_relu(const float* __restrict__ h,
                                                      const int* __restrict__ row_start,
                                                      const int* __restrict__ counts,
                                                      const int* __restrict__ csr_src,
                                                      const float* __restrict__ csr_w,
                                                      const float* __restrict__ bias,
                                                      float* __restrict__ out) {
    const int node = blockIdx.x;
    const int d = threadIdx.x;
    const int beg = row_start[node];
    const int cnt = counts[node];
    float acc = 0.f;
    for (int e = 0; e < cnt; e++) {
        const int s = csr_src[beg + e];
        const float w = csr_w[beg + e];
        acc = fmaf(w, h[(size_t)s * D + d], acc);
    }
    acc += bias[d];
    out[(size_t)node * D + d] = fmaxf(acc, 0.f);
}

// ---------------- final dense: out[M x 40] = h @ Wd + bd ----------------
// block (64,4): 4 rows per block, Wd staged in LDS (40KB)

__global__ __launch_bounds__(256) void dense_out(const float* __restrict__ h,
                                                 const float* __restrict__ Wd,
                                                 const float* __restrict__ bd,
                                                 float* __restrict__ out, int M) {
    __shared__ float w[D * NCLS];
    for (int i = threadIdx.y * 64 + threadIdx.x; i < D * NCLS; i += 256) w[i] = Wd[i];
    __syncthreads();
    const int row = blockIdx.x * 4 + threadIdx.y;
    const int c = threadIdx.x;
    if (row >= M || c >= NCLS) return;
    float acc = 0.f;
    for (int k = 0; k < D; k++) acc = fmaf(h[(size_t)row * D + k], w[k * NCLS + c], acc);
    out[(size_t)row * NCLS + c] = acc + bd[c];
}

// ---------------- launch ----------------

extern "C" void kernel_launch(void* const* d_in, const int* in_sizes, int n_in,
                              void* d_out, int out_size, void* d_ws, size_t ws_size,
                              hipStream_t stream) {
    const float* x    = (const float*)d_in[0];
    const int*   esrc = (const int*)d_in[1];
    const int*   edst = (const int*)d_in[2];
    const float* ew   = (const float*)d_in[3];
    const float* W1   = (const float*)d_in[4];
    const float* b1   = (const float*)d_in[5];
    const float* W2   = (const float*)d_in[6];
    const float* b2   = (const float*)d_in[7];
    const float* W3   = (const float*)d_in[8];
    const float* b3   = (const float*)d_in[9];
    const float* Wd   = (const float*)d_in[10];
    const float* bd   = (const float*)d_in[11];
    float* out = (float*)d_out;

    const int M  = in_sizes[0] / D;   // 100000
    const int NE = in_sizes[1];       // 3200000

    char* p = (char*)d_ws;
    auto alloc = [&](size_t bytes) -> char* {
        char* r = p;
        p += (bytes + 255) & ~(size_t)255;
        return r;
    };
    float* hA       = (float*)alloc((size_t)M * D * sizeof(float));
    float* hB       = (float*)alloc((size_t)M * D * sizeof(float));
    int*   csr_src  = (int*)alloc((size_t)NE * sizeof(int));
    float* csr_w    = (float*)alloc((size_t)NE * sizeof(float));
    int*   counts   = (int*)alloc((size_t)M * sizeof(int));
    int*   row_start= (int*)alloc((size_t)M * sizeof(int));
    int*   cursor   = (int*)alloc((size_t)M * sizeof(int));
    int*   blk_sums = (int*)alloc(4096);
    int*   blk_off  = (int*)alloc(4096);

    hipMemsetAsync(counts, 0, (size_t)M * sizeof(int), stream);
    hipMemsetAsync(cursor, 0, (size_t)M * sizeof(int), stream);

    const int nb = (M + 255) / 256;   // 391
    count_dst<<<(NE + 255) / 256, 256, 0, stream>>>(edst, NE, counts);
    scan1<<<nb, 256, 0, stream>>>(counts, M, row_start, blk_sums);
    scan2<<<1, 512, 0, stream>>>(blk_sums, nb, blk_off);
    scan3<<<nb, 256, 0, stream>>>(row_start, counts, blk_off, M);
    scatter_edges<<<(NE + 255) / 256, 256, 0, stream>>>(esrc, edst, ew, NE, row_start,
                                                        cursor, csr_src, csr_w);

    dim3 gg((M + 63) / 64, 4);
    gemm256<<<gg, 256, 0, stream>>>(x, W1, hA, M);
    spmm_bias_relu<<<M, 256, 0, stream>>>(hA, row_start, counts, csr_src, csr_w, b1, hB);
    gemm256<<<gg, 256, 0, stream>>>(hB, W2, hA, M);
    spmm_bias_relu<<<M, 256, 0, stream>>>(hA, row_start, counts, csr_src, csr_w, b2, hB);
    gemm256<<<gg, 256, 0, stream>>>(hB, W3, hA, M);
    spmm_bias_relu<<<M, 256, 0, stream>>>(hA, row_start, counts, csr_src, csr_w, b3, hB);

    dense_out<<<(M + 3) / 4, dim3(64, 4), 0, stream>>>(hB, Wd, bd, out, M);
}

// Round 2
// 1838.277 us; speedup vs baseline: 1.6159x; 1.6159x over previous
//
#include <hip/hip_runtime.h>

#define D 256
#define NCLS 40

typedef __attribute__((ext_vector_type(8))) short bf16x8;
typedef __attribute__((ext_vector_type(4))) float f32x4;

__device__ __forceinline__ unsigned short f2b(float f) {
    unsigned u = __float_as_uint(f);
    u += 0x7fffu + ((u >> 16) & 1u);   // RNE
    return (unsigned short)(u >> 16);
}
__device__ __forceinline__ float b2f(unsigned short s) {
    return __uint_as_float(((unsigned)s) << 16);
}

// ---------------- CSR build ----------------

__global__ __launch_bounds__(256) void count_dst(const int* __restrict__ dst, int ne,
                                                 int* __restrict__ counts) {
    int e = blockIdx.x * 256 + threadIdx.x;
    if (e < ne) atomicAdd(&counts[dst[e]], 1);
}

__global__ __launch_bounds__(256) void scan1(const int* __restrict__ counts, int n,
                                             int* __restrict__ incl, int* __restrict__ blk_sums) {
    __shared__ int s[256];
    int tx = threadIdx.x;
    int i = blockIdx.x * 256 + tx;
    int v = (i < n) ? counts[i] : 0;
    s[tx] = v;
    __syncthreads();
    for (int off = 1; off < 256; off <<= 1) {
        int t = (tx >= off) ? s[tx - off] : 0;
        __syncthreads();
        s[tx] += t;
        __syncthreads();
    }
    if (i < n) incl[i] = s[tx];
    if (tx == 255) blk_sums[blockIdx.x] = s[255];
}

__global__ __launch_bounds__(512) void scan2(const int* __restrict__ blk_sums, int nb,
                                             int* __restrict__ blk_off) {
    __shared__ int s[512];
    int tx = threadIdx.x;
    int v = (tx < nb) ? blk_sums[tx] : 0;
    s[tx] = v;
    __syncthreads();
    for (int off = 1; off < 512; off <<= 1) {
        int t = (tx >= off) ? s[tx - off] : 0;
        __syncthreads();
        s[tx] += t;
        __syncthreads();
    }
    if (tx < nb) blk_off[tx] = s[tx] - v;   // exclusive
}

__global__ __launch_bounds__(256) void scan3(int* __restrict__ row_start,
                                             const int* __restrict__ counts,
                                             const int* __restrict__ blk_off, int n) {
    int i = blockIdx.x * 256 + threadIdx.x;
    if (i < n) row_start[i] = blk_off[blockIdx.x] + row_start[i] - counts[i];
}

__global__ __launch_bounds__(256) void scatter_edges(const int* __restrict__ src,
                                                     const int* __restrict__ dst,
                                                     const float* __restrict__ w, int ne,
                                                     const int* __restrict__ row_start,
                                                     int* __restrict__ cursor,
                                                     int* __restrict__ csr_src,
                                                     float* __restrict__ csr_w) {
    int e = blockIdx.x * 256 + threadIdx.x;
    if (e >= ne) return;
    int d = dst[e];
    int pos = row_start[d] + atomicAdd(&cursor[d], 1);
    csr_src[pos] = src[e];
    csr_w[pos]   = w[e];
}

// ---------------- weight prep: fp32 W[256][256] -> bf16 hi/lo, MFMA-fragment-packed ----
// packed index: (((t*8 + ks)*64 + lane)*8 + e)
//   n = t*16 + (lane&15) ; k = ks*32 + ((lane>>4)&3)*8 + e
__global__ __launch_bounds__(256) void prep_weights(const float* __restrict__ W,
                                                    short* __restrict__ Bhi,
                                                    short* __restrict__ Blo) {
    int i = blockIdx.x * 256 + threadIdx.x;       // 0..65535
    int e = i & 7, lane = (i >> 3) & 63, ks = (i >> 9) & 7, t = i >> 12;
    int n = t * 16 + (lane & 15);
    int k = ks * 32 + ((lane >> 4) & 3) * 8 + e;
    float w = W[k * D + n];
    unsigned short hi = f2b(w);
    float rem = w - b2f(hi);
    Bhi[i] = (short)hi;
    Blo[i] = (short)f2b(rem);
}

// ---------------- MFMA GEMM: C[M x 256] = A[M x 256] @ (Whi + Wlo) ----------------
// block = 256 threads = 4 waves; wave = 16 rows x 256 cols; K=256 in 8 steps of 32.
// A fragment: lane l -> row (l&15), k = ks*32 + (l>>4)*8 + e  (contiguous 16B)
// C/D: col = lane&15, row = (lane>>4)*4 + reg  [guide §3, m89-verified]
template<int AFP32>
__global__ __launch_bounds__(256) void gemm_mfma(const float* __restrict__ A32,
                                                 const short* __restrict__ A16,
                                                 const short* __restrict__ Bhi,
                                                 const short* __restrict__ Blo,
                                                 short* __restrict__ Cout, int M) {
    const int lane = threadIdx.x & 63;
    const int wave = threadIdx.x >> 6;
    const int r  = lane & 15;
    const int kg = (lane >> 4) & 3;
    const int row0 = blockIdx.x * 64 + wave * 16;
    int arow = row0 + r;
    if (arow >= M) arow = M - 1;

    f32x4 acc[16];
#pragma unroll
    for (int t = 0; t < 16; t++) acc[t] = (f32x4){0.f, 0.f, 0.f, 0.f};

    const size_t abase = (size_t)arow * D + kg * 8;

#pragma unroll
    for (int ks = 0; ks < 8; ks++) {
        bf16x8 af;
        if (AFP32) {
            const float* ap = A32 + abase + ks * 32;
            float4 lo = *(const float4*)ap;
            float4 hi = *(const float4*)(ap + 4);
            af[0] = (short)f2b(lo.x); af[1] = (short)f2b(lo.y);
            af[2] = (short)f2b(lo.z); af[3] = (short)f2b(lo.w);
            af[4] = (short)f2b(hi.x); af[5] = (short)f2b(hi.y);
            af[6] = (short)f2b(hi.z); af[7] = (short)f2b(hi.w);
        } else {
            af = *(const bf16x8*)(A16 + abase + ks * 32);
        }
        const short* bh = Bhi + ks * 512 + lane * 8;
        const short* bl = Blo + ks * 512 + lane * 8;
#pragma unroll
        for (int t = 0; t < 16; t++) {
            bf16x8 h8 = *(const bf16x8*)(bh + t * 4096);
            bf16x8 l8 = *(const bf16x8*)(bl + t * 4096);
            acc[t] = __builtin_amdgcn_mfma_f32_16x16x32_bf16(af, h8, acc[t], 0, 0, 0);
            acc[t] = __builtin_amdgcn_mfma_f32_16x16x32_bf16(af, l8, acc[t], 0, 0, 0);
        }
    }

#pragma unroll
    for (int t = 0; t < 16; t++) {
#pragma unroll
        for (int rg = 0; rg < 4; rg++) {
            int orow = row0 + kg * 4 + rg;
            if (orow < M)
                Cout[(size_t)orow * D + t * 16 + r] = (short)f2b(acc[t][rg]);
        }
    }
}

// ---------------- SpMM (bf16 gather) + bias + ReLU -> bf16 ----------------
// block 256 = 2 nodes x 128 threads; thread t handles dims {2t, 2t+1} (one 4B load/edge)
__global__ __launch_bounds__(256) void spmm_bias_relu16(const short* __restrict__ h,
                                                        const int* __restrict__ row_start,
                                                        const int* __restrict__ counts,
                                                        const int* __restrict__ csr_src,
                                                        const float* __restrict__ csr_w,
                                                        const float* __restrict__ bias,
                                                        short* __restrict__ out, int M) {
    const int node = blockIdx.x * 2 + (threadIdx.x >> 7);
    if (node >= M) return;
    const int t = threadIdx.x & 127;
    const int beg = row_start[node];
    const int cnt = counts[node];
    const int*   sp = csr_src + beg;
    const float* wp = csr_w + beg;
    float a0 = 0.f, a1 = 0.f, c0 = 0.f, c1 = 0.f;
    int e = 0;
    for (; e + 2 <= cnt; e += 2) {
        int s0 = sp[e], s1 = sp[e + 1];
        float w0 = wp[e], w1 = wp[e + 1];
        unsigned v0 = *(const unsigned*)(h + ((size_t)s0 << 8) + t * 2);
        unsigned v1 = *(const unsigned*)(h + ((size_t)s1 << 8) + t * 2);
        a0 = fmaf(w0, b2f((unsigned short)v0), a0);
        a1 = fmaf(w0, b2f((unsigned short)(v0 >> 16)), a1);
        c0 = fmaf(w1, b2f((unsigned short)v1), c0);
        c1 = fmaf(w1, b2f((unsigned short)(v1 >> 16)), c1);
    }
    if (e < cnt) {
        int s0 = sp[e];
        float w0 = wp[e];
        unsigned v0 = *(const unsigned*)(h + ((size_t)s0 << 8) + t * 2);
        a0 = fmaf(w0, b2f((unsigned short)v0), a0);
        a1 = fmaf(w0, b2f((unsigned short)(v0 >> 16)), a1);
    }
    a0 += c0; a1 += c1;
    float2 b = *(const float2*)(bias + t * 2);
    a0 = fmaxf(a0 + b.x, 0.f);
    a1 = fmaxf(a1 + b.y, 0.f);
    unsigned o = (unsigned)f2b(a0) | ((unsigned)f2b(a1) << 16);
    *(unsigned*)(out + ((size_t)node << 8) + t * 2) = o;
}

// ---------------- final dense: out[M x 40] = h(bf16) @ Wd + bd ----------------
__global__ __launch_bounds__(256) void dense_out16(const short* __restrict__ h,
                                                   const float* __restrict__ Wd,
                                                   const float* __restrict__ bd,
                                                   float* __restrict__ out, int M) {
    __shared__ float w[D * NCLS];
    for (int i = threadIdx.y * 64 + threadIdx.x; i < D * NCLS; i += 256) w[i] = Wd[i];
    __syncthreads();
    const int row = blockIdx.x * 4 + threadIdx.y;
    const int c = threadIdx.x;
    if (row >= M || c >= NCLS) return;
    float acc = 0.f;
    const short* hp = h + (size_t)row * D;
    for (int k2 = 0; k2 < 128; k2++) {
        unsigned v = *(const unsigned*)(hp + k2 * 2);
        acc = fmaf(b2f((unsigned short)v),         w[(k2 * 2)     * NCLS + c], acc);
        acc = fmaf(b2f((unsigned short)(v >> 16)), w[(k2 * 2 + 1) * NCLS + c], acc);
    }
    out[(size_t)row * NCLS + c] = acc + bd[c];
}

// ---------------- launch ----------------

extern "C" void kernel_launch(void* const* d_in, const int* in_sizes, int n_in,
                              void* d_out, int out_size, void* d_ws, size_t ws_size,
                              hipStream_t stream) {
    const float* x    = (const float*)d_in[0];
    const int*   esrc = (const int*)d_in[1];
    const int*   edst = (const int*)d_in[2];
    const float* ew   = (const float*)d_in[3];
    const float* W1   = (const float*)d_in[4];
    const float* b1   = (const float*)d_in[5];
    const float* W2   = (const float*)d_in[6];
    const float* b2   = (const float*)d_in[7];
    const float* W3   = (const float*)d_in[8];
    const float* b3   = (const float*)d_in[9];
    const float* Wd   = (const float*)d_in[10];
    const float* bd   = (const float*)d_in[11];
    float* out = (float*)d_out;

    const int M  = in_sizes[0] / D;   // 100000
    const int NE = in_sizes[1];       // 3200000

    char* p = (char*)d_ws;
    auto alloc = [&](size_t bytes) -> char* {
        char* r = p;
        p += (bytes + 255) & ~(size_t)255;
        return r;
    };
    short* hA       = (short*)alloc((size_t)M * D * sizeof(short));
    short* hB       = (short*)alloc((size_t)M * D * sizeof(short));
    int*   csr_src  = (int*)alloc((size_t)NE * sizeof(int));
    float* csr_w    = (float*)alloc((size_t)NE * sizeof(float));
    int*   counts   = (int*)alloc((size_t)M * sizeof(int));
    int*   row_start= (int*)alloc((size_t)M * sizeof(int));
    int*   cursor   = (int*)alloc((size_t)M * sizeof(int));
    int*   blk_sums = (int*)alloc(4096);
    int*   blk_off  = (int*)alloc(4096);
    short* B1h = (short*)alloc(D * D * sizeof(short));
    short* B1l = (short*)alloc(D * D * sizeof(short));
    short* B2h = (short*)alloc(D * D * sizeof(short));
    short* B2l = (short*)alloc(D * D * sizeof(short));
    short* B3h = (short*)alloc(D * D * sizeof(short));
    short* B3l = (short*)alloc(D * D * sizeof(short));

    hipMemsetAsync(counts, 0, (size_t)M * sizeof(int), stream);
    hipMemsetAsync(cursor, 0, (size_t)M * sizeof(int), stream);

    const int nb = (M + 255) / 256;   // 391
    count_dst<<<(NE + 255) / 256, 256, 0, stream>>>(edst, NE, counts);
    scan1<<<nb, 256, 0, stream>>>(counts, M, row_start, blk_sums);
    scan2<<<1, 512, 0, stream>>>(blk_sums, nb, blk_off);
    scan3<<<nb, 256, 0, stream>>>(row_start, counts, blk_off, M);
    scatter_edges<<<(NE + 255) / 256, 256, 0, stream>>>(esrc, edst, ew, NE, row_start,
                                                        cursor, csr_src, csr_w);

    prep_weights<<<256, 256, 0, stream>>>(W1, B1h, B1l);
    prep_weights<<<256, 256, 0, stream>>>(W2, B2h, B2l);
    prep_weights<<<256, 256, 0, stream>>>(W3, B3h, B3l);

    const int gg = (M + 63) / 64;          // 1563
    const int gs = (M + 1) / 2;            // 50000

    gemm_mfma<1><<<gg, 256, 0, stream>>>(x, nullptr, B1h, B1l, hA, M);
    spmm_bias_relu16<<<gs, 256, 0, stream>>>(hA, row_start, counts, csr_src, csr_w, b1, hB, M);
    gemm_mfma<0><<<gg, 256, 0, stream>>>(nullptr, hB, B2h, B2l, hA, M);
    spmm_bias_relu16<<<gs, 256, 0, stream>>>(hA, row_start, counts, csr_src, csr_w, b2, hB, M);
    gemm_mfma<0><<<gg, 256, 0, stream>>>(nullptr, hB, B3h, B3l, hA, M);
    spmm_bias_relu16<<<gs, 256, 0, stream>>>(hA, row_start, counts, csr_src, csr_w, b3, hB, M);

    dense_out16<<<(M + 3) / 4, dim3(64, 4), 0, stream>>>(hB, Wd, bd, out, M);
}

// Round 3
// 1373.565 us; speedup vs baseline: 2.1626x; 1.3383x over previous
//
#include <hip/hip_runtime.h>

#define D 256
#define NCLS 40

typedef __attribute__((ext_vector_type(8))) short bf16x8;
typedef __attribute__((ext_vector_type(4))) float f32x4;

__device__ __forceinline__ unsigned short f2b(float f) {
    unsigned u = __float_as_uint(f);
    u += 0x7fffu + ((u >> 16) & 1u);   // RNE
    return (unsigned short)(u >> 16);
}
__device__ __forceinline__ float b2f(unsigned short s) {
    return __uint_as_float(((unsigned)s) << 16);
}

// ---------------- CSR build ----------------

__global__ __launch_bounds__(256) void count_dst(const int* __restrict__ dst, int ne,
                                                 int* __restrict__ counts) {
    int e = blockIdx.x * 256 + threadIdx.x;
    if (e < ne) atomicAdd(&counts[dst[e]], 1);
}

__global__ __launch_bounds__(256) void scan1(const int* __restrict__ counts, int n,
                                             int* __restrict__ incl, int* __restrict__ blk_sums) {
    __shared__ int s[256];
    int tx = threadIdx.x;
    int i = blockIdx.x * 256 + tx;
    int v = (i < n) ? counts[i] : 0;
    s[tx] = v;
    __syncthreads();
    for (int off = 1; off < 256; off <<= 1) {
        int t = (tx >= off) ? s[tx - off] : 0;
        __syncthreads();
        s[tx] += t;
        __syncthreads();
    }
    if (i < n) incl[i] = s[tx];
    if (tx == 255) blk_sums[blockIdx.x] = s[255];
}

__global__ __launch_bounds__(512) void scan2(const int* __restrict__ blk_sums, int nb,
                                             int* __restrict__ blk_off) {
    __shared__ int s[512];
    int tx = threadIdx.x;
    int v = (tx < nb) ? blk_sums[tx] : 0;
    s[tx] = v;
    __syncthreads();
    for (int off = 1; off < 512; off <<= 1) {
        int t = (tx >= off) ? s[tx - off] : 0;
        __syncthreads();
        s[tx] += t;
        __syncthreads();
    }
    if (tx < nb) blk_off[tx] = s[tx] - v;   // exclusive
}

__global__ __launch_bounds__(256) void scan3(int* __restrict__ row_start,
                                             const int* __restrict__ counts,
                                             const int* __restrict__ blk_off, int n) {
    int i = blockIdx.x * 256 + threadIdx.x;
    if (i < n) row_start[i] = blk_off[blockIdx.x] + row_start[i] - counts[i];
}

__global__ __launch_bounds__(256) void scatter_edges(const int* __restrict__ src,
                                                     const int* __restrict__ dst,
                                                     const float* __restrict__ w, int ne,
                                                     const int* __restrict__ row_start,
                                                     int* __restrict__ cursor,
                                                     int* __restrict__ csr_src,
                                                     float* __restrict__ csr_w) {
    int e = blockIdx.x * 256 + threadIdx.x;
    if (e >= ne) return;
    int d = dst[e];
    int pos = row_start[d] + atomicAdd(&cursor[d], 1);
    csr_src[pos] = src[e];
    csr_w[pos]   = w[e];
}

// ---------------- weight prep: fp32 W[256][256] -> bf16 hi/lo, ks-major packed ----
// Bpack[i], i = ((((ks*2 + hl)*16 + t)*64 + lane)*8 + e)
//   n = t*16 + (lane&15) ; k = ks*32 + ((lane>>4)&3)*8 + e
__global__ __launch_bounds__(256) void prep_weights2(const float* __restrict__ W,
                                                     short* __restrict__ Bpack) {
    int i = blockIdx.x * 256 + threadIdx.x;       // 0..131071
    int e = i & 7, lane = (i >> 3) & 63, t = (i >> 9) & 15, hl = (i >> 13) & 1, ks = (i >> 14) & 7;
    int n = t * 16 + (lane & 15);
    int k = ks * 32 + ((lane >> 4) & 3) * 8 + e;
    float w = W[k * D + n];
    unsigned short hi = f2b(w);
    Bpack[i] = (hl == 0) ? (short)hi : (short)f2b(w - b2f(hi));
}

// ---------------- MFMA GEMM: C[M x 256] = A[M x 256] @ (Whi + Wlo) ----------------
// block = 256 threads = 4 waves; 128 rows/block, 32 rows/wave (2 fragment sets).
// B (hi+lo) staged per-ks (32 KB) into double-buffered LDS, shared by all waves.
// A fragment: lane l -> row (l&15), k = ks*32 + (l>>4)*8 + e  (contiguous 16B)
// C/D: col = lane&15, row = (lane>>4)*4 + reg
template<int AFP32>
__global__ __launch_bounds__(256) void gemm_mfma2(const float* __restrict__ A32,
                                                  const short* __restrict__ A16,
                                                  const short* __restrict__ Bpack,
                                                  short* __restrict__ Cout, int M) {
    __shared__ short Bs[2][16384];   // 2 x 32 KB
    const int tid = threadIdx.x;
    const int lane = tid & 63, wave = tid >> 6;
    const int r = lane & 15, kg = lane >> 4;
    const int row_base = blockIdx.x * 128 + wave * 32;
    int ar0 = row_base + r;      if (ar0 >= M) ar0 = M - 1;
    int ar1 = row_base + 16 + r; if (ar1 >= M) ar1 = M - 1;

    f32x4 acc0[16], acc1[16];
#pragma unroll
    for (int t = 0; t < 16; t++) {
        acc0[t] = (f32x4){0.f, 0.f, 0.f, 0.f};
        acc1[t] = (f32x4){0.f, 0.f, 0.f, 0.f};
    }

    bf16x8 af0[8], af1[8];
    if (!AFP32) {
#pragma unroll
        for (int ks = 0; ks < 8; ks++) {
            af0[ks] = *(const bf16x8*)(A16 + (size_t)ar0 * D + ks * 32 + kg * 8);
            af1[ks] = *(const bf16x8*)(A16 + (size_t)ar1 * D + ks * 32 + kg * 8);
        }
    }

    auto stage = [&](int ks, int buf) {
        const short* src = Bpack + ks * 16384;
#pragma unroll
        for (int j = 0; j < 8; j++)
            *(bf16x8*)&Bs[buf][j * 2048 + tid * 8] = *(const bf16x8*)(src + j * 2048 + tid * 8);
    };

    stage(0, 0);
#pragma unroll
    for (int ks = 0; ks < 8; ks++) {
        __syncthreads();
        bf16x8 a0k, a1k;
        if (AFP32) {
            const float* p0 = A32 + (size_t)ar0 * D + ks * 32 + kg * 8;
            const float* p1 = A32 + (size_t)ar1 * D + ks * 32 + kg * 8;
            float4 x0 = *(const float4*)p0, x1 = *(const float4*)(p0 + 4);
            float4 y0 = *(const float4*)p1, y1 = *(const float4*)(p1 + 4);
            a0k[0] = (short)f2b(x0.x); a0k[1] = (short)f2b(x0.y);
            a0k[2] = (short)f2b(x0.z); a0k[3] = (short)f2b(x0.w);
            a0k[4] = (short)f2b(x1.x); a0k[5] = (short)f2b(x1.y);
            a0k[6] = (short)f2b(x1.z); a0k[7] = (short)f2b(x1.w);
            a1k[0] = (short)f2b(y0.x); a1k[1] = (short)f2b(y0.y);
            a1k[2] = (short)f2b(y0.z); a1k[3] = (short)f2b(y0.w);
            a1k[4] = (short)f2b(y1.x); a1k[5] = (short)f2b(y1.y);
            a1k[6] = (short)f2b(y1.z); a1k[7] = (short)f2b(y1.w);
        } else {
            a0k = af0[ks];
            a1k = af1[ks];
        }
#pragma unroll
        for (int t = 0; t < 16; t++) {
            bf16x8 h8 = *(const bf16x8*)&Bs[ks & 1][(t * 64 + lane) * 8];
            bf16x8 l8 = *(const bf16x8*)&Bs[ks & 1][((16 + t) * 64 + lane) * 8];
            acc0[t] = __builtin_amdgcn_mfma_f32_16x16x32_bf16(a0k, h8, acc0[t], 0, 0, 0);
            acc1[t] = __builtin_amdgcn_mfma_f32_16x16x32_bf16(a1k, h8, acc1[t], 0, 0, 0);
            acc0[t] = __builtin_amdgcn_mfma_f32_16x16x32_bf16(a0k, l8, acc0[t], 0, 0, 0);
            acc1[t] = __builtin_amdgcn_mfma_f32_16x16x32_bf16(a1k, l8, acc1[t], 0, 0, 0);
        }
        if (ks < 7) {
            __syncthreads();
            stage(ks + 1, (ks + 1) & 1);
        }
    }

#pragma unroll
    for (int t = 0; t < 16; t++) {
#pragma unroll
        for (int rg = 0; rg < 4; rg++) {
            int o0 = row_base + kg * 4 + rg;
            int o1 = o0 + 16;
            if (o0 < M) Cout[(size_t)o0 * D + t * 16 + r] = (short)f2b(acc0[t][rg]);
            if (o1 < M) Cout[(size_t)o1 * D + t * 16 + r] = (short)f2b(acc1[t][rg]);
        }
    }
}

// ---------------- SpMM (bf16 gather) + bias + ReLU -> bf16 ----------------
// block 256 = 4 nodes x 64 threads; thread t covers dims [4t, 4t+4) (8 B loads).
// 4-edge unroll -> 32 B outstanding gather bytes per thread.
__global__ __launch_bounds__(256) void spmm4(const short* __restrict__ h,
                                             const int* __restrict__ row_start,
                                             const int* __restrict__ counts,
                                             const int* __restrict__ csr_src,
                                             const float* __restrict__ csr_w,
                                             const float* __restrict__ bias,
                                             short* __restrict__ out, int M) {
    const int node = blockIdx.x * 4 + (threadIdx.x >> 6);
    if (node >= M) return;
    const int t = threadIdx.x & 63;
    const int beg = row_start[node];
    const int cnt = counts[node];
    const int*   sp = csr_src + beg;
    const float* wp = csr_w + beg;
    const size_t doff = (size_t)t * 4;

    float a0 = 0.f, a1 = 0.f, a2 = 0.f, a3 = 0.f;
    float c0 = 0.f, c1 = 0.f, c2 = 0.f, c3 = 0.f;

    int e = 0;
    int pre = (4 - (beg & 3)) & 3;          // align sp/wp to 16 B for vector loads
    if (pre > cnt) pre = cnt;
    for (; e < pre; e++) {
        int s = sp[e];
        float w = wp[e];
        ushort4 v = *(const ushort4*)(h + ((size_t)s << 8) + doff);
        a0 = fmaf(w, b2f(v.x), a0); a1 = fmaf(w, b2f(v.y), a1);
        a2 = fmaf(w, b2f(v.z), a2); a3 = fmaf(w, b2f(v.w), a3);
    }
    for (; e + 4 <= cnt; e += 4) {
        int4   s = *(const int4*)(sp + e);
        float4 w = *(const float4*)(wp + e);
        ushort4 v0 = *(const ushort4*)(h + ((size_t)s.x << 8) + doff);
        ushort4 v1 = *(const ushort4*)(h + ((size_t)s.y << 8) + doff);
        ushort4 v2 = *(const ushort4*)(h + ((size_t)s.z << 8) + doff);
        ushort4 v3 = *(const ushort4*)(h + ((size_t)s.w << 8) + doff);
        a0 = fmaf(w.x, b2f(v0.x), a0); a1 = fmaf(w.x, b2f(v0.y), a1);
        a2 = fmaf(w.x, b2f(v0.z), a2); a3 = fmaf(w.x, b2f(v0.w), a3);
        c0 = fmaf(w.y, b2f(v1.x), c0); c1 = fmaf(w.y, b2f(v1.y), c1);
        c2 = fmaf(w.y, b2f(v1.z), c2); c3 = fmaf(w.y, b2f(v1.w), c3);
        a0 = fmaf(w.z, b2f(v2.x), a0); a1 = fmaf(w.z, b2f(v2.y), a1);
        a2 = fmaf(w.z, b2f(v2.z), a2); a3 = fmaf(w.z, b2f(v2.w), a3);
        c0 = fmaf(w.w, b2f(v3.x), c0); c1 = fmaf(w.w, b2f(v3.y), c1);
        c2 = fmaf(w.w, b2f(v3.z), c2); c3 = fmaf(w.w, b2f(v3.w), c3);
    }
    for (; e < cnt; e++) {
        int s = sp[e];
        float w = wp[e];
        ushort4 v = *(const ushort4*)(h + ((size_t)s << 8) + doff);
        a0 = fmaf(w, b2f(v.x), a0); a1 = fmaf(w, b2f(v.y), a1);
        a2 = fmaf(w, b2f(v.z), a2); a3 = fmaf(w, b2f(v.w), a3);
    }
    a0 += c0; a1 += c1; a2 += c2; a3 += c3;

    float4 b = *(const float4*)(bias + t * 4);
    a0 = fmaxf(a0 + b.x, 0.f);
    a1 = fmaxf(a1 + b.y, 0.f);
    a2 = fmaxf(a2 + b.z, 0.f);
    a3 = fmaxf(a3 + b.w, 0.f);
    uint2 o;
    o.x = (unsigned)f2b(a0) | ((unsigned)f2b(a1) << 16);
    o.y = (unsigned)f2b(a2) | ((unsigned)f2b(a3) << 16);
    *(uint2*)(out + ((size_t)node << 8) + doff) = o;
}

// ---------------- final dense: out[M x 40] = h(bf16) @ Wd + bd ----------------
__global__ __launch_bounds__(256) void dense_out16(const short* __restrict__ h,
                                                   const float* __restrict__ Wd,
                                                   const float* __restrict__ bd,
                                                   float* __restrict__ out, int M) {
    __shared__ float w[D * NCLS];
    for (int i = threadIdx.y * 64 + threadIdx.x; i < D * NCLS; i += 256) w[i] = Wd[i];
    __syncthreads();
    const int row = blockIdx.x * 4 + threadIdx.y;
    const int c = threadIdx.x;
    if (row >= M || c >= NCLS) return;
    float acc = 0.f;
    const short* hp = h + (size_t)row * D;
    for (int k2 = 0; k2 < 128; k2++) {
        unsigned v = *(const unsigned*)(hp + k2 * 2);
        acc = fmaf(b2f((unsigned short)v),         w[(k2 * 2)     * NCLS + c], acc);
        acc = fmaf(b2f((unsigned short)(v >> 16)), w[(k2 * 2 + 1) * NCLS + c], acc);
    }
    out[(size_t)row * NCLS + c] = acc + bd[c];
}

// ---------------- launch ----------------

extern "C" void kernel_launch(void* const* d_in, const int* in_sizes, int n_in,
                              void* d_out, int out_size, void* d_ws, size_t ws_size,
                              hipStream_t stream) {
    const float* x    = (const float*)d_in[0];
    const int*   esrc = (const int*)d_in[1];
    const int*   edst = (const int*)d_in[2];
    const float* ew   = (const float*)d_in[3];
    const float* W1   = (const float*)d_in[4];
    const float* b1   = (const float*)d_in[5];
    const float* W2   = (const float*)d_in[6];
    const float* b2   = (const float*)d_in[7];
    const float* W3   = (const float*)d_in[8];
    const float* b3   = (const float*)d_in[9];
    const float* Wd   = (const float*)d_in[10];
    const float* bd   = (const float*)d_in[11];
    float* out = (float*)d_out;

    const int M  = in_sizes[0] / D;   // 100000
    const int NE = in_sizes[1];       // 3200000

    char* p = (char*)d_ws;
    auto alloc = [&](size_t bytes) -> char* {
        char* r = p;
        p += (bytes + 255) & ~(size_t)255;
        return r;
    };
    short* hA       = (short*)alloc((size_t)M * D * sizeof(short));
    short* hB       = (short*)alloc((size_t)M * D * sizeof(short));
    int*   csr_src  = (int*)alloc((size_t)NE * sizeof(int));
    float* csr_w    = (float*)alloc((size_t)NE * sizeof(float));
    int*   counts   = (int*)alloc((size_t)M * sizeof(int));
    int*   row_start= (int*)alloc((size_t)M * sizeof(int));
    int*   cursor   = (int*)alloc((size_t)M * sizeof(int));
    int*   blk_sums = (int*)alloc(4096);
    int*   blk_off  = (int*)alloc(4096);
    short* B1p = (short*)alloc(2 * D * D * sizeof(short));
    short* B2p = (short*)alloc(2 * D * D * sizeof(short));
    short* B3p = (short*)alloc(2 * D * D * sizeof(short));

    hipMemsetAsync(counts, 0, (size_t)M * sizeof(int), stream);
    hipMemsetAsync(cursor, 0, (size_t)M * sizeof(int), stream);

    const int nb = (M + 255) / 256;   // 391
    count_dst<<<(NE + 255) / 256, 256, 0, stream>>>(edst, NE, counts);
    scan1<<<nb, 256, 0, stream>>>(counts, M, row_start, blk_sums);
    scan2<<<1, 512, 0, stream>>>(blk_sums, nb, blk_off);
    scan3<<<nb, 256, 0, stream>>>(row_start, counts, blk_off, M);
    scatter_edges<<<(NE + 255) / 256, 256, 0, stream>>>(esrc, edst, ew, NE, row_start,
                                                        cursor, csr_src, csr_w);

    prep_weights2<<<512, 256, 0, stream>>>(W1, B1p);
    prep_weights2<<<512, 256, 0, stream>>>(W2, B2p);
    prep_weights2<<<512, 256, 0, stream>>>(W3, B3p);

    const int gg = (M + 127) / 128;        // 782
    const int gs = (M + 3) / 4;            // 25000

    gemm_mfma2<1><<<gg, 256, 0, stream>>>(x, nullptr, B1p, hA, M);
    spmm4<<<gs, 256, 0, stream>>>(hA, row_start, counts, csr_src, csr_w, b1, hB, M);
    gemm_mfma2<0><<<gg, 256, 0, stream>>>(nullptr, hB, B2p, hA, M);
    spmm4<<<gs, 256, 0, stream>>>(hA, row_start, counts, csr_src, csr_w, b2, hB, M);
    gemm_mfma2<0><<<gg, 256, 0, stream>>>(nullptr, hB, B3p, hA, M);
    spmm4<<<gs, 256, 0, stream>>>(hA, row_start, counts, csr_src, csr_w, b3, hB, M);

    dense_out16<<<(M + 3) / 4, dim3(64, 4), 0, stream>>>(hB, Wd, bd, out, M);
}

// Round 4
// 1309.656 us; speedup vs baseline: 2.2681x; 1.0488x over previous
//
#include <hip/hip_runtime.h>

#define D 256
#define NCLS 40

typedef __attribute__((ext_vector_type(8))) short bf16x8;
typedef __attribute__((ext_vector_type(4))) float f32x4;

__device__ __forceinline__ unsigned short f2b(float f) {
    unsigned u = __float_as_uint(f);
    u += 0x7fffu + ((u >> 16) & 1u);   // RNE
    return (unsigned short)(u >> 16);
}
__device__ __forceinline__ float b2f(unsigned short s) {
    return __uint_as_float(((unsigned)s) << 16);
}

// ---------------- CSR build ----------------

__global__ __launch_bounds__(256) void count_dst(const int* __restrict__ dst, int ne,
                                                 int* __restrict__ counts) {
    int e = blockIdx.x * 256 + threadIdx.x;
    if (e < ne) atomicAdd(&counts[dst[e]], 1);
}

__global__ __launch_bounds__(256) void scan1(const int* __restrict__ counts, int n,
                                             int* __restrict__ incl, int* __restrict__ blk_sums) {
    __shared__ int s[256];
    int tx = threadIdx.x;
    int i = blockIdx.x * 256 + tx;
    int v = (i < n) ? counts[i] : 0;
    s[tx] = v;
    __syncthreads();
    for (int off = 1; off < 256; off <<= 1) {
        int t = (tx >= off) ? s[tx - off] : 0;
        __syncthreads();
        s[tx] += t;
        __syncthreads();
    }
    if (i < n) incl[i] = s[tx];
    if (tx == 255) blk_sums[blockIdx.x] = s[255];
}

__global__ __launch_bounds__(512) void scan2(const int* __restrict__ blk_sums, int nb,
                                             int* __restrict__ blk_off) {
    __shared__ int s[512];
    int tx = threadIdx.x;
    int v = (tx < nb) ? blk_sums[tx] : 0;
    s[tx] = v;
    __syncthreads();
    for (int off = 1; off < 512; off <<= 1) {
        int t = (tx >= off) ? s[tx - off] : 0;
        __syncthreads();
        s[tx] += t;
        __syncthreads();
    }
    if (tx < nb) blk_off[tx] = s[tx] - v;   // exclusive
}

__global__ __launch_bounds__(256) void scan3(int* __restrict__ row_start,
                                             const int* __restrict__ counts,
                                             const int* __restrict__ blk_off, int n) {
    int i = blockIdx.x * 256 + threadIdx.x;
    if (i < n) row_start[i] = blk_off[blockIdx.x] + row_start[i] - counts[i];
}

// one 8-byte payload per edge: {src, w_bits}
__global__ __launch_bounds__(256) void scatter_edges2(const int* __restrict__ src,
                                                      const int* __restrict__ dst,
                                                      const float* __restrict__ w, int ne,
                                                      const int* __restrict__ row_start,
                                                      int* __restrict__ cursor,
                                                      int2* __restrict__ pairs) {
    int e = blockIdx.x * 256 + threadIdx.x;
    if (e >= ne) return;
    int d = dst[e];
    int pos = row_start[d] + atomicAdd(&cursor[d], 1);
    pairs[pos] = make_int2(src[e], __float_as_int(w[e]));
}

// ---------------- weight prep: fp32 W[256][256] -> bf16 hi/lo, ks-major packed ----
// Bpack[i], i = ((((ks*2 + hl)*16 + t)*64 + lane)*8 + e)
//   n = t*16 + (lane&15) ; k = ks*32 + ((lane>>4)&3)*8 + e
__global__ __launch_bounds__(256) void prep_weights2(const float* __restrict__ W,
                                                     short* __restrict__ Bpack) {
    int i = blockIdx.x * 256 + threadIdx.x;       // 0..131071
    int e = i & 7, lane = (i >> 3) & 63, t = (i >> 9) & 15, hl = (i >> 13) & 1, ks = (i >> 14) & 7;
    int n = t * 16 + (lane & 15);
    int k = ks * 32 + ((lane >> 4) & 3) * 8 + e;
    float w = W[k * D + n];
    unsigned short hi = f2b(w);
    Bpack[i] = (hl == 0) ? (short)hi : (short)f2b(w - b2f(hi));
}

// ---------------- MFMA GEMM: C[M x 256] = A[M x 256] @ (Whi + Wlo) ----------------
// block = 256 threads = 4 waves; 128 rows/block, 32 rows/wave (2 fragment sets).
// B (hi+lo) staged per-ks (32 KB) into double-buffered LDS via global_load_lds(16B),
// issued before the MFMA block so loads fly under compute (m97 pattern).
template<int AFP32>
__global__ __launch_bounds__(256) void gemm_mfma3(const float* __restrict__ A32,
                                                  const short* __restrict__ A16,
                                                  const short* __restrict__ Bpack,
                                                  short* __restrict__ Cout, int M) {
    __shared__ short Bs[2][16384];   // 2 x 32 KB
    const int tid = threadIdx.x;
    const int lane = tid & 63, wv = tid >> 6;
    const int r = lane & 15, kg = lane >> 4;
    const int row_base = blockIdx.x * 128 + wv * 32;
    int ar0 = row_base + r;      if (ar0 >= M) ar0 = M - 1;
    int ar1 = row_base + 16 + r; if (ar1 >= M) ar1 = M - 1;

    f32x4 acc0[16], acc1[16];
#pragma unroll
    for (int t = 0; t < 16; t++) {
        acc0[t] = (f32x4){0.f, 0.f, 0.f, 0.f};
        acc1[t] = (f32x4){0.f, 0.f, 0.f, 0.f};
    }

    bf16x8 af0[8], af1[8];
    if (!AFP32) {
#pragma unroll
        for (int ks = 0; ks < 8; ks++) {
            af0[ks] = *(const bf16x8*)(A16 + (size_t)ar0 * D + ks * 32 + kg * 8);
            af1[ks] = *(const bf16x8*)(A16 + (size_t)ar1 * D + ks * 32 + kg * 8);
        }
    }

    // wave-linear async stage: LDS dest = uniform base + lane*16B; global src per-lane
    auto stage = [&](int ks, int buf) {
        const short* src = Bpack + ks * 16384 + wv * 512 + lane * 8;
        short* dst = &Bs[buf][wv * 512];
#pragma unroll
        for (int j = 0; j < 8; j++) {
            __builtin_amdgcn_global_load_lds(
                (const __attribute__((address_space(1))) unsigned*)(src + j * 2048),
                (__attribute__((address_space(3))) unsigned*)(dst + j * 2048),
                16, 0, 0);
        }
    };

    stage(0, 0);
#pragma unroll
    for (int ks = 0; ks < 8; ks++) {
        __syncthreads();                 // drains stage(ks) (vmcnt) + guards buffer reuse
        if (ks < 7) stage(ks + 1, (ks + 1) & 1);   // async into other buffer, overlaps MFMA
        bf16x8 a0k, a1k;
        if (AFP32) {
            const float* p0 = A32 + (size_t)ar0 * D + ks * 32 + kg * 8;
            const float* p1 = A32 + (size_t)ar1 * D + ks * 32 + kg * 8;
            float4 x0 = *(const float4*)p0, x1 = *(const float4*)(p0 + 4);
            float4 y0 = *(const float4*)p1, y1 = *(const float4*)(p1 + 4);
            a0k[0] = (short)f2b(x0.x); a0k[1] = (short)f2b(x0.y);
            a0k[2] = (short)f2b(x0.z); a0k[3] = (short)f2b(x0.w);
            a0k[4] = (short)f2b(x1.x); a0k[5] = (short)f2b(x1.y);
            a0k[6] = (short)f2b(x1.z); a0k[7] = (short)f2b(x1.w);
            a1k[0] = (short)f2b(y0.x); a1k[1] = (short)f2b(y0.y);
            a1k[2] = (short)f2b(y0.z); a1k[3] = (short)f2b(y0.w);
            a1k[4] = (short)f2b(y1.x); a1k[5] = (short)f2b(y1.y);
            a1k[6] = (short)f2b(y1.z); a1k[7] = (short)f2b(y1.w);
        } else {
            a0k = af0[ks];
            a1k = af1[ks];
        }
#pragma unroll
        for (int t = 0; t < 16; t++) {
            bf16x8 h8 = *(const bf16x8*)&Bs[ks & 1][(t * 64 + lane) * 8];
            bf16x8 l8 = *(const bf16x8*)&Bs[ks & 1][((16 + t) * 64 + lane) * 8];
            acc0[t] = __builtin_amdgcn_mfma_f32_16x16x32_bf16(a0k, h8, acc0[t], 0, 0, 0);
            acc1[t] = __builtin_amdgcn_mfma_f32_16x16x32_bf16(a1k, h8, acc1[t], 0, 0, 0);
            acc0[t] = __builtin_amdgcn_mfma_f32_16x16x32_bf16(a0k, l8, acc0[t], 0, 0, 0);
            acc1[t] = __builtin_amdgcn_mfma_f32_16x16x32_bf16(a1k, l8, acc1[t], 0, 0, 0);
        }
    }

#pragma unroll
    for (int t = 0; t < 16; t++) {
#pragma unroll
        for (int rg = 0; rg < 4; rg++) {
            int o0 = row_base + kg * 4 + rg;
            int o1 = o0 + 16;
            if (o0 < M) Cout[(size_t)o0 * D + t * 16 + r] = (short)f2b(acc0[t][rg]);
            if (o1 < M) Cout[(size_t)o1 * D + t * 16 + r] = (short)f2b(acc1[t][rg]);
        }
    }
}

// ---------------- SpMM (bf16 gather) + bias + ReLU -> bf16 ----------------
// block 256 = 8 nodes x 32 lanes; lane t covers dims [8t, 8t+8) (16 B gathers).
// 8-edge unroll -> 128 B outstanding gather bytes per lane.
__global__ __launch_bounds__(256) void spmm8(const short* __restrict__ h,
                                             const int* __restrict__ row_start,
                                             const int* __restrict__ counts,
                                             const int2* __restrict__ pairs,
                                             const float* __restrict__ bias,
                                             short* __restrict__ out, int M) {
    const int node = blockIdx.x * 8 + (threadIdx.x >> 5);
    if (node >= M) return;
    const int t = threadIdx.x & 31;
    const int beg = row_start[node];
    const int cnt = counts[node];
    const int2* pp = pairs + beg;
    const size_t doff = (size_t)t * 8;

    float a0 = 0.f, a1 = 0.f, a2 = 0.f, a3 = 0.f;
    float a4 = 0.f, a5 = 0.f, a6 = 0.f, a7 = 0.f;

    int e = 0;
    for (; e + 8 <= cnt; e += 8) {
        int2 p0 = pp[e],     p1 = pp[e + 1], p2 = pp[e + 2], p3 = pp[e + 3];
        int2 p4 = pp[e + 4], p5 = pp[e + 5], p6 = pp[e + 6], p7 = pp[e + 7];
        uint4 v0 = *(const uint4*)(h + ((size_t)p0.x << 8) + doff);
        uint4 v1 = *(const uint4*)(h + ((size_t)p1.x << 8) + doff);
        uint4 v2 = *(const uint4*)(h + ((size_t)p2.x << 8) + doff);
        uint4 v3 = *(const uint4*)(h + ((size_t)p3.x << 8) + doff);
        uint4 v4 = *(const uint4*)(h + ((size_t)p4.x << 8) + doff);
        uint4 v5 = *(const uint4*)(h + ((size_t)p5.x << 8) + doff);
        uint4 v6 = *(const uint4*)(h + ((size_t)p6.x << 8) + doff);
        uint4 v7 = *(const uint4*)(h + ((size_t)p7.x << 8) + doff);
#define ACC(V, P)                                                          \
        {                                                                  \
            float w = __int_as_float(P.y);                                 \
            a0 = fmaf(w, b2f((unsigned short)(V.x)), a0);                  \
            a1 = fmaf(w, b2f((unsigned short)(V.x >> 16)), a1);            \
            a2 = fmaf(w, b2f((unsigned short)(V.y)), a2);                  \
            a3 = fmaf(w, b2f((unsigned short)(V.y >> 16)), a3);            \
            a4 = fmaf(w, b2f((unsigned short)(V.z)), a4);                  \
            a5 = fmaf(w, b2f((unsigned short)(V.z >> 16)), a5);            \
            a6 = fmaf(w, b2f((unsigned short)(V.w)), a6);                  \
            a7 = fmaf(w, b2f((unsigned short)(V.w >> 16)), a7);            \
        }
        ACC(v0, p0) ACC(v1, p1) ACC(v2, p2) ACC(v3, p3)
        ACC(v4, p4) ACC(v5, p5) ACC(v6, p6) ACC(v7, p7)
    }
    for (; e < cnt; e++) {
        int2 p = pp[e];
        uint4 v = *(const uint4*)(h + ((size_t)p.x << 8) + doff);
        ACC(v, p)
    }
#undef ACC

    float4 ba = *(const float4*)(bias + t * 8);
    float4 bb = *(const float4*)(bias + t * 8 + 4);
    a0 = fmaxf(a0 + ba.x, 0.f); a1 = fmaxf(a1 + ba.y, 0.f);
    a2 = fmaxf(a2 + ba.z, 0.f); a3 = fmaxf(a3 + ba.w, 0.f);
    a4 = fmaxf(a4 + bb.x, 0.f); a5 = fmaxf(a5 + bb.y, 0.f);
    a6 = fmaxf(a6 + bb.z, 0.f); a7 = fmaxf(a7 + bb.w, 0.f);
    uint4 o;
    o.x = (unsigned)f2b(a0) | ((unsigned)f2b(a1) << 16);
    o.y = (unsigned)f2b(a2) | ((unsigned)f2b(a3) << 16);
    o.z = (unsigned)f2b(a4) | ((unsigned)f2b(a5) << 16);
    o.w = (unsigned)f2b(a6) | ((unsigned)f2b(a7) << 16);
    *(uint4*)(out + ((size_t)node << 8) + doff) = o;
}

// ---------------- final dense: out[M x 40] = h(bf16) @ Wd + bd ----------------
__global__ __launch_bounds__(256) void dense_out16(const short* __restrict__ h,
                                                   const float* __restrict__ Wd,
                                                   const float* __restrict__ bd,
                                                   float* __restrict__ out, int M) {
    __shared__ float w[D * NCLS];
    for (int i = threadIdx.y * 64 + threadIdx.x; i < D * NCLS; i += 256) w[i] = Wd[i];
    __syncthreads();
    const int row = blockIdx.x * 4 + threadIdx.y;
    const int c = threadIdx.x;
    if (row >= M || c >= NCLS) return;
    float acc = 0.f;
    const short* hp = h + (size_t)row * D;
    for (int k2 = 0; k2 < 128; k2++) {
        unsigned v = *(const unsigned*)(hp + k2 * 2);
        acc = fmaf(b2f((unsigned short)v),         w[(k2 * 2)     * NCLS + c], acc);
        acc = fmaf(b2f((unsigned short)(v >> 16)), w[(k2 * 2 + 1) * NCLS + c], acc);
    }
    out[(size_t)row * NCLS + c] = acc + bd[c];
}

// ---------------- launch ----------------

extern "C" void kernel_launch(void* const* d_in, const int* in_sizes, int n_in,
                              void* d_out, int out_size, void* d_ws, size_t ws_size,
                              hipStream_t stream) {
    const float* x    = (const float*)d_in[0];
    const int*   esrc = (const int*)d_in[1];
    const int*   edst = (const int*)d_in[2];
    const float* ew   = (const float*)d_in[3];
    const float* W1   = (const float*)d_in[4];
    const float* b1   = (const float*)d_in[5];
    const float* W2   = (const float*)d_in[6];
    const float* b2   = (const float*)d_in[7];
    const float* W3   = (const float*)d_in[8];
    const float* b3   = (const float*)d_in[9];
    const float* Wd   = (const float*)d_in[10];
    const float* bd   = (const float*)d_in[11];
    float* out = (float*)d_out;

    const int M  = in_sizes[0] / D;   // 100000
    const int NE = in_sizes[1];       // 3200000

    char* p = (char*)d_ws;
    auto alloc = [&](size_t bytes) -> char* {
        char* r = p;
        p += (bytes + 255) & ~(size_t)255;
        return r;
    };
    short* hA       = (short*)alloc((size_t)M * D * sizeof(short));
    short* hB       = (short*)alloc((size_t)M * D * sizeof(short));
    int2*  pairs    = (int2*)alloc((size_t)NE * sizeof(int2));
    int*   counts   = (int*)alloc((size_t)M * sizeof(int));
    int*   row_start= (int*)alloc((size_t)M * sizeof(int));
    int*   cursor   = (int*)alloc((size_t)M * sizeof(int));
    int*   blk_sums = (int*)alloc(4096);
    int*   blk_off  = (int*)alloc(4096);
    short* B1p = (short*)alloc(2 * D * D * sizeof(short));
    short* B2p = (short*)alloc(2 * D * D * sizeof(short));
    short* B3p = (short*)alloc(2 * D * D * sizeof(short));

    hipMemsetAsync(counts, 0, (size_t)M * sizeof(int), stream);
    hipMemsetAsync(cursor, 0, (size_t)M * sizeof(int), stream);

    const int nb = (M + 255) / 256;   // 391
    count_dst<<<(NE + 255) / 256, 256, 0, stream>>>(edst, NE, counts);
    scan1<<<nb, 256, 0, stream>>>(counts, M, row_start, blk_sums);
    scan2<<<1, 512, 0, stream>>>(blk_sums, nb, blk_off);
    scan3<<<nb, 256, 0, stream>>>(row_start, counts, blk_off, M);
    scatter_edges2<<<(NE + 255) / 256, 256, 0, stream>>>(esrc, edst, ew, NE, row_start,
                                                         cursor, pairs);

    prep_weights2<<<512, 256, 0, stream>>>(W1, B1p);
    prep_weights2<<<512, 256, 0, stream>>>(W2, B2p);
    prep_weights2<<<512, 256, 0, stream>>>(W3, B3p);

    const int gg = (M + 127) / 128;        // 782
    const int gs = (M + 7) / 8;            // 12500

    gemm_mfma3<1><<<gg, 256, 0, stream>>>(x, nullptr, B1p, hA, M);
    spmm8<<<gs, 256, 0, stream>>>(hA, row_start, counts, pairs, b1, hB, M);
    gemm_mfma3<0><<<gg, 256, 0, stream>>>(nullptr, hB, B2p, hA, M);
    spmm8<<<gs, 256, 0, stream>>>(hA, row_start, counts, pairs, b2, hB, M);
    gemm_mfma3<0><<<gg, 256, 0, stream>>>(nullptr, hB, B3p, hA, M);
    spmm8<<<gs, 256, 0, stream>>>(hA, row_start, counts, pairs, b3, hB, M);

    dense_out16<<<(M + 3) / 4, dim3(64, 4), 0, stream>>>(hB, Wd, bd, out, M);
}

// Round 5
// 1047.317 us; speedup vs baseline: 2.8362x; 1.2505x over previous
//
#include <hip/hip_runtime.h>

#define D 256
#define NCLS 40

typedef __attribute__((ext_vector_type(8))) short bf16x8;
typedef __attribute__((ext_vector_type(4))) float f32x4;

__device__ __forceinline__ unsigned short f2b(float f) {
    unsigned u = __float_as_uint(f);
    u += 0x7fffu + ((u >> 16) & 1u);   // RNE
    return (unsigned short)(u >> 16);
}
__device__ __forceinline__ float b2f(unsigned short s) {
    return __uint_as_float(((unsigned)s) << 16);
}

// ---------------- CSR build ----------------

// count + per-edge rank in one pass (atomicAdd returns old = rank)
__global__ __launch_bounds__(256) void count_rank(const int* __restrict__ dst, int ne,
                                                  int* __restrict__ counts,
                                                  unsigned short* __restrict__ rank) {
    int e = blockIdx.x * 256 + threadIdx.x;
    if (e < ne) rank[e] = (unsigned short)atomicAdd(&counts[dst[e]], 1);
}

__global__ __launch_bounds__(256) void scan1(const int* __restrict__ counts, int n,
                                             int* __restrict__ incl, int* __restrict__ blk_sums) {
    __shared__ int s[256];
    int tx = threadIdx.x;
    int i = blockIdx.x * 256 + tx;
    int v = (i < n) ? counts[i] : 0;
    s[tx] = v;
    __syncthreads();
    for (int off = 1; off < 256; off <<= 1) {
        int t = (tx >= off) ? s[tx - off] : 0;
        __syncthreads();
        s[tx] += t;
        __syncthreads();
    }
    if (i < n) incl[i] = s[tx];
    if (tx == 255) blk_sums[blockIdx.x] = s[255];
}

__global__ __launch_bounds__(512) void scan2(const int* __restrict__ blk_sums, int nb,
                                             int* __restrict__ blk_off) {
    __shared__ int s[512];
    int tx = threadIdx.x;
    int v = (tx < nb) ? blk_sums[tx] : 0;
    s[tx] = v;
    __syncthreads();
    for (int off = 1; off < 512; off <<= 1) {
        int t = (tx >= off) ? s[tx - off] : 0;
        __syncthreads();
        s[tx] += t;
        __syncthreads();
    }
    if (tx < nb) blk_off[tx] = s[tx] - v;   // exclusive
}

__global__ __launch_bounds__(256) void scan3(int* __restrict__ row_start,
                                             const int* __restrict__ counts,
                                             const int* __restrict__ blk_off, int n) {
    int i = blockIdx.x * 256 + threadIdx.x;
    if (i < n) row_start[i] = blk_off[blockIdx.x] + row_start[i] - counts[i];
}

// pure random 8B writes, no atomics (rank precomputed)
__global__ __launch_bounds__(256) void scatter_edges3(const int* __restrict__ src,
                                                      const int* __restrict__ dst,
                                                      const float* __restrict__ w, int ne,
                                                      const int* __restrict__ row_start,
                                                      const unsigned short* __restrict__ rank,
                                                      int2* __restrict__ pairs) {
    int e = blockIdx.x * 256 + threadIdx.x;
    if (e >= ne) return;
    int pos = row_start[dst[e]] + (int)rank[e];
    pairs[pos] = make_int2(src[e], __float_as_int(w[e]));
}

// ---------------- weight prep: fp32 W[256][256] -> bf16 (hi only), ks-major packed ----
// Bpack[i], i = (((ks*16 + t)*64 + lane)*8 + e)
//   n = t*16 + (lane&15) ; k = ks*32 + ((lane>>4)&3)*8 + e
__global__ __launch_bounds__(256) void prep_weights3(const float* __restrict__ W,
                                                     short* __restrict__ Bpack) {
    int i = blockIdx.x * 256 + threadIdx.x;       // 0..65535
    int e = i & 7, lane = (i >> 3) & 63, t = (i >> 9) & 15, ks = (i >> 13) & 7;
    int n = t * 16 + (lane & 15);
    int k = ks * 32 + ((lane >> 4) & 3) * 8 + e;
    Bpack[i] = (short)f2b(W[k * D + n]);
}

// ---- Wd prep: fp32 Wd[256][40] -> bf16 hi/lo frags, N padded to 48 (3 tiles) ----
// Wdp[i], i = ((ks*6 + hl*3 + t)*512) + lane*8 + e    (24576 shorts = 48 KB)
__global__ __launch_bounds__(256) void prep_wd(const float* __restrict__ Wd,
                                               short* __restrict__ Wdp) {
    int i = blockIdx.x * 256 + threadIdx.x;       // 0..24575
    int e = i & 7, lane = (i >> 3) & 63;
    int q = i >> 9;                // 0..47
    int t = q % 3, hl = (q / 3) & 1, ks = q / 6;
    int n = t * 16 + (lane & 15);
    int k = ks * 32 + ((lane >> 4) & 3) * 8 + e;
    float v = (n < NCLS) ? Wd[k * NCLS + n] : 0.f;
    unsigned short hi = f2b(v);
    Wdp[i] = hl ? (short)f2b(v - b2f(hi)) : (short)hi;
}

// ---------------- MFMA GEMM: C[M x 256] = A[M x 256] @ W(bf16) ----------------
// block = 256 threads = 4 waves; 128 rows/block, 32 rows/wave.
// B staged per-ks (16 KB) into double-buffered LDS via global_load_lds(16B).
template<int AFP32>
__global__ __launch_bounds__(256) void gemm_mfma4(const float* __restrict__ A32,
                                                  const short* __restrict__ A16,
                                                  const short* __restrict__ Bpack,
                                                  short* __restrict__ Cout, int M) {
    __shared__ short Bs[2][8192];   // 2 x 16 KB
    const int tid = threadIdx.x;
    const int lane = tid & 63;
    const int r = lane & 15, kg = lane >> 4;
    const int wv = tid >> 6;
    const int row_base = blockIdx.x * 128 + wv * 32;
    int ar0 = row_base + r;      if (ar0 >= M) ar0 = M - 1;
    int ar1 = row_base + 16 + r; if (ar1 >= M) ar1 = M - 1;

    f32x4 acc0[16], acc1[16];
#pragma unroll
    for (int t = 0; t < 16; t++) {
        acc0[t] = (f32x4){0.f, 0.f, 0.f, 0.f};
        acc1[t] = (f32x4){0.f, 0.f, 0.f, 0.f};
    }

    bf16x8 af0[8], af1[8];
    if (!AFP32) {
#pragma unroll
        for (int ks = 0; ks < 8; ks++) {
            af0[ks] = *(const bf16x8*)(A16 + (size_t)ar0 * D + ks * 32 + kg * 8);
            af1[ks] = *(const bf16x8*)(A16 + (size_t)ar1 * D + ks * 32 + kg * 8);
        }
    }

    // linear async stage: per-thread 2 x 16B chunks, wave-linear LDS dest
    auto stage = [&](int ks, int buf) {
        const short* src = Bpack + ks * 8192 + tid * 8;
        short* dst = &Bs[buf][tid * 8];
#pragma unroll
        for (int j = 0; j < 4; j++) {
            __builtin_amdgcn_global_load_lds(
                (const __attribute__((address_space(1))) unsigned*)(src + j * 2048),
                (__attribute__((address_space(3))) unsigned*)(dst + j * 2048),
                16, 0, 0);
        }
    };

    stage(0, 0);
#pragma unroll
    for (int ks = 0; ks < 8; ks++) {
        __syncthreads();                 // drains stage(ks) + guards buffer reuse
        if (ks < 7) stage(ks + 1, (ks + 1) & 1);
        bf16x8 a0k, a1k;
        if (AFP32) {
            const float* p0 = A32 + (size_t)ar0 * D + ks * 32 + kg * 8;
            const float* p1 = A32 + (size_t)ar1 * D + ks * 32 + kg * 8;
            float4 x0 = *(const float4*)p0, x1 = *(const float4*)(p0 + 4);
            float4 y0 = *(const float4*)p1, y1 = *(const float4*)(p1 + 4);
            a0k[0] = (short)f2b(x0.x); a0k[1] = (short)f2b(x0.y);
            a0k[2] = (short)f2b(x0.z); a0k[3] = (short)f2b(x0.w);
            a0k[4] = (short)f2b(x1.x); a0k[5] = (short)f2b(x1.y);
            a0k[6] = (short)f2b(x1.z); a0k[7] = (short)f2b(x1.w);
            a1k[0] = (short)f2b(y0.x); a1k[1] = (short)f2b(y0.y);
            a1k[2] = (short)f2b(y0.z); a1k[3] = (short)f2b(y0.w);
            a1k[4] = (short)f2b(y1.x); a1k[5] = (short)f2b(y1.y);
            a1k[6] = (short)f2b(y1.z); a1k[7] = (short)f2b(y1.w);
        } else {
            a0k = af0[ks];
            a1k = af1[ks];
        }
#pragma unroll
        for (int t = 0; t < 16; t++) {
            bf16x8 h8 = *(const bf16x8*)&Bs[ks & 1][t * 512 + lane * 8];
            acc0[t] = __builtin_amdgcn_mfma_f32_16x16x32_bf16(a0k, h8, acc0[t], 0, 0, 0);
            acc1[t] = __builtin_amdgcn_mfma_f32_16x16x32_bf16(a1k, h8, acc1[t], 0, 0, 0);
        }
    }

#pragma unroll
    for (int t = 0; t < 16; t++) {
#pragma unroll
        for (int rg = 0; rg < 4; rg++) {
            int o0 = row_base + kg * 4 + rg;
            int o1 = o0 + 16;
            if (o0 < M) Cout[(size_t)o0 * D + t * 16 + r] = (short)f2b(acc0[t][rg]);
            if (o1 < M) Cout[(size_t)o1 * D + t * 16 + r] = (short)f2b(acc1[t][rg]);
        }
    }
}

// ---------------- SpMM (bf16 gather) + bias + ReLU -> bf16 ----------------
// block 256 = 8 nodes x 32 lanes; lane t covers dims [8t, 8t+8) (16 B gathers).
__global__ __launch_bounds__(256) void spmm8(const short* __restrict__ h,
                                             const int* __restrict__ row_start,
                                             const int* __restrict__ counts,
                                             const int2* __restrict__ pairs,
                                             const float* __restrict__ bias,
                                             short* __restrict__ out, int M) {
    const int node = blockIdx.x * 8 + (threadIdx.x >> 5);
    if (node >= M) return;
    const int t = threadIdx.x & 31;
    const int beg = row_start[node];
    const int cnt = counts[node];
    const int2* pp = pairs + beg;
    const size_t doff = (size_t)t * 8;

    float a0 = 0.f, a1 = 0.f, a2 = 0.f, a3 = 0.f;
    float a4 = 0.f, a5 = 0.f, a6 = 0.f, a7 = 0.f;

    int e = 0;
    for (; e + 8 <= cnt; e += 8) {
        int2 p0 = pp[e],     p1 = pp[e + 1], p2 = pp[e + 2], p3 = pp[e + 3];
        int2 p4 = pp[e + 4], p5 = pp[e + 5], p6 = pp[e + 6], p7 = pp[e + 7];
        uint4 v0 = *(const uint4*)(h + ((size_t)p0.x << 8) + doff);
        uint4 v1 = *(const uint4*)(h + ((size_t)p1.x << 8) + doff);
        uint4 v2 = *(const uint4*)(h + ((size_t)p2.x << 8) + doff);
        uint4 v3 = *(const uint4*)(h + ((size_t)p3.x << 8) + doff);
        uint4 v4 = *(const uint4*)(h + ((size_t)p4.x << 8) + doff);
        uint4 v5 = *(const uint4*)(h + ((size_t)p5.x << 8) + doff);
        uint4 v6 = *(const uint4*)(h + ((size_t)p6.x << 8) + doff);
        uint4 v7 = *(const uint4*)(h + ((size_t)p7.x << 8) + doff);
#define ACC(V, P)                                                          \
        {                                                                  \
            float w = __int_as_float(P.y);                                 \
            a0 = fmaf(w, b2f((unsigned short)(V.x)), a0);                  \
            a1 = fmaf(w, b2f((unsigned short)(V.x >> 16)), a1);            \
            a2 = fmaf(w, b2f((unsigned short)(V.y)), a2);                  \
            a3 = fmaf(w, b2f((unsigned short)(V.y >> 16)), a3);            \
            a4 = fmaf(w, b2f((unsigned short)(V.z)), a4);                  \
            a5 = fmaf(w, b2f((unsigned short)(V.z >> 16)), a5);            \
            a6 = fmaf(w, b2f((unsigned short)(V.w)), a6);                  \
            a7 = fmaf(w, b2f((unsigned short)(V.w >> 16)), a7);            \
        }
        ACC(v0, p0) ACC(v1, p1) ACC(v2, p2) ACC(v3, p3)
        ACC(v4, p4) ACC(v5, p5) ACC(v6, p6) ACC(v7, p7)
    }
    for (; e < cnt; e++) {
        int2 p = pp[e];
        uint4 v = *(const uint4*)(h + ((size_t)p.x << 8) + doff);
        ACC(v, p)
    }
#undef ACC

    float4 ba = *(const float4*)(bias + t * 8);
    float4 bb = *(const float4*)(bias + t * 8 + 4);
    a0 = fmaxf(a0 + ba.x, 0.f); a1 = fmaxf(a1 + ba.y, 0.f);
    a2 = fmaxf(a2 + ba.z, 0.f); a3 = fmaxf(a3 + ba.w, 0.f);
    a4 = fmaxf(a4 + bb.x, 0.f); a5 = fmaxf(a5 + bb.y, 0.f);
    a6 = fmaxf(a6 + bb.z, 0.f); a7 = fmaxf(a7 + bb.w, 0.f);
    uint4 o;
    o.x = (unsigned)f2b(a0) | ((unsigned)f2b(a1) << 16);
    o.y = (unsigned)f2b(a2) | ((unsigned)f2b(a3) << 16);
    o.z = (unsigned)f2b(a4) | ((unsigned)f2b(a5) << 16);
    o.w = (unsigned)f2b(a6) | ((unsigned)f2b(a7) << 16);
    *(uint4*)(out + ((size_t)node << 8) + doff) = o;
}

// ---------------- final dense via MFMA: out[M x 40] = h(bf16) @ (Wd hi+lo) + bd ----
// block 256 = 4 waves x 16 rows; Wd frags (48 KB) staged once in LDS.
__global__ __launch_bounds__(256) void dense_mfma(const short* __restrict__ h,
                                                  const short* __restrict__ Wdp,
                                                  const float* __restrict__ bd,
                                                  float* __restrict__ out, int M) {
    __shared__ short Ws[24576];   // 48 KB
    const int tid = threadIdx.x;
    const int lane = tid & 63;
    const int r = lane & 15, kg = lane >> 4;
    const int row_base = blockIdx.x * 64 + (tid >> 6) * 16;
    int arow = row_base + r; if (arow >= M) arow = M - 1;

#pragma unroll
    for (int j = 0; j < 12; j++) {
        __builtin_amdgcn_global_load_lds(
            (const __attribute__((address_space(1))) unsigned*)(Wdp + j * 2048 + tid * 8),
            (__attribute__((address_space(3))) unsigned*)(&Ws[j * 2048 + tid * 8]),
            16, 0, 0);
    }

    f32x4 acc[3];
#pragma unroll
    for (int t = 0; t < 3; t++) acc[t] = (f32x4){0.f, 0.f, 0.f, 0.f};

    bf16x8 af[8];
#pragma unroll
    for (int ks = 0; ks < 8; ks++)
        af[ks] = *(const bf16x8*)(h + (size_t)arow * D + ks * 32 + kg * 8);

    __syncthreads();   // drain gload_lds

#pragma unroll
    for (int ks = 0; ks < 8; ks++) {
#pragma unroll
        for (int t = 0; t < 3; t++) {
            bf16x8 h8 = *(const bf16x8*)&Ws[(ks * 6 + t) * 512 + lane * 8];
            bf16x8 l8 = *(const bf16x8*)&Ws[(ks * 6 + 3 + t) * 512 + lane * 8];
            acc[t] = __builtin_amdgcn_mfma_f32_16x16x32_bf16(af[ks], h8, acc[t], 0, 0, 0);
            acc[t] = __builtin_amdgcn_mfma_f32_16x16x32_bf16(af[ks], l8, acc[t], 0, 0, 0);
        }
    }

#pragma unroll
    for (int t = 0; t < 3; t++) {
#pragma unroll
        for (int rg = 0; rg < 4; rg++) {
            int orow = row_base + kg * 4 + rg;
            int col = t * 16 + r;
            if (orow < M && col < NCLS)
                out[(size_t)orow * NCLS + col] = acc[t][rg] + bd[col];
        }
    }
}

// ---------------- launch ----------------

extern "C" void kernel_launch(void* const* d_in, const int* in_sizes, int n_in,
                              void* d_out, int out_size, void* d_ws, size_t ws_size,
                              hipStream_t stream) {
    const float* x    = (const float*)d_in[0];
    const int*   esrc = (const int*)d_in[1];
    const int*   edst = (const int*)d_in[2];
    const float* ew   = (const float*)d_in[3];
    const float* W1   = (const float*)d_in[4];
    const float* b1   = (const float*)d_in[5];
    const float* W2   = (const float*)d_in[6];
    const float* b2   = (const float*)d_in[7];
    const float* W3   = (const float*)d_in[8];
    const float* b3   = (const float*)d_in[9];
    const float* Wd   = (const float*)d_in[10];
    const float* bd   = (const float*)d_in[11];
    float* out = (float*)d_out;

    const int M  = in_sizes[0] / D;   // 100000
    const int NE = in_sizes[1];       // 3200000

    char* p = (char*)d_ws;
    auto alloc = [&](size_t bytes) -> char* {
        char* r = p;
        p += (bytes + 255) & ~(size_t)255;
        return r;
    };
    short* hA        = (short*)alloc((size_t)M * D * sizeof(short));
    short* hB        = (short*)alloc((size_t)M * D * sizeof(short));
    int2*  pairs     = (int2*)alloc((size_t)NE * sizeof(int2));
    unsigned short* rank = (unsigned short*)alloc((size_t)NE * sizeof(unsigned short));
    int*   counts    = (int*)alloc((size_t)M * sizeof(int));
    int*   row_start = (int*)alloc((size_t)M * sizeof(int));
    int*   blk_sums  = (int*)alloc(4096);
    int*   blk_off   = (int*)alloc(4096);
    short* B1p = (short*)alloc(D * D * sizeof(short));
    short* B2p = (short*)alloc(D * D * sizeof(short));
    short* B3p = (short*)alloc(D * D * sizeof(short));
    short* Wdp = (short*)alloc(24576 * sizeof(short));

    hipMemsetAsync(counts, 0, (size_t)M * sizeof(int), stream);

    const int nb = (M + 255) / 256;   // 391
    count_rank<<<(NE + 255) / 256, 256, 0, stream>>>(edst, NE, counts, rank);
    scan1<<<nb, 256, 0, stream>>>(counts, M, row_start, blk_sums);
    scan2<<<1, 512, 0, stream>>>(blk_sums, nb, blk_off);
    scan3<<<nb, 256, 0, stream>>>(row_start, counts, blk_off, M);
    scatter_edges3<<<(NE + 255) / 256, 256, 0, stream>>>(esrc, edst, ew, NE, row_start,
                                                         rank, pairs);

    prep_weights3<<<256, 256, 0, stream>>>(W1, B1p);
    prep_weights3<<<256, 256, 0, stream>>>(W2, B2p);
    prep_weights3<<<256, 256, 0, stream>>>(W3, B3p);
    prep_wd<<<96, 256, 0, stream>>>(Wd, Wdp);

    const int gg = (M + 127) / 128;        // 782
    const int gs = (M + 7) / 8;            // 12500

    gemm_mfma4<1><<<gg, 256, 0, stream>>>(x, nullptr, B1p, hA, M);
    spmm8<<<gs, 256, 0, stream>>>(hA, row_start, counts, pairs, b1, hB, M);
    gemm_mfma4<0><<<gg, 256, 0, stream>>>(nullptr, hB, B2p, hA, M);
    spmm8<<<gs, 256, 0, stream>>>(hA, row_start, counts, pairs, b2, hB, M);
    gemm_mfma4<0><<<gg, 256, 0, stream>>>(nullptr, hB, B3p, hA, M);
    spmm8<<<gs, 256, 0, stream>>>(hA, row_start, counts, pairs, b3, hB, M);

    dense_mfma<<<(M + 63) / 64, 256, 0, stream>>>(hB, Wdp, bd, out, M);
}